// Round 3
// baseline (497.637 us; speedup 1.0000x reference)
//
#include <hip/hip_runtime.h>
#include <math.h>

#define N    512
#define CS   384
#define CZ   128
#define H    12
#define D    16
#define PQ   4
#define PV   8
#define CAT_W 2112

#define WC 0.23570226039551584f  /* sqrt(2/(9*4)) */
#define WL 0.5773502691896258f   /* sqrt(1/3) */

// workspace offsets (in floats)
#define O_Q    0          /* Q   [512][192] row-major */
#define O_KT   98304      /* Kt  [192][512] transposed */
#define O_VT   196608     /* VT  [192][512] transposed */
#define O_QF   294912     /* raw local points [512][144] */
#define O_KF   368640
#define O_VF   442368     /* [512][288] */
#define O_GQ   589824     /* gq  [512][144] row-major */
#define O_GKT  663552     /* gkT [144][512] transposed */
#define O_GVT  737280     /* gvT [288][512] transposed */
#define O_BIAS 884736     /* biasT->attn [512][12][512]; reused for k_out partials */
#define O_PART O_BIAS
#define O_CAT  4030464    /* [512][2112] */
/* total 5,111,808 floats = 20.4 MB */

#define KSPLIT 8
#define KCH    264        /* 2112 / 8 */
#define ALD    516        /* padded LDS stride for attn rows (16B-aligned, bank-spread) */

// ---------------- projections: s @ {w_q,w_k,w_v,w_qf,w_kf,w_vf} ----------------
__global__ __launch_bounds__(256) void k_proj(
    const float* __restrict__ s,
    const float* __restrict__ wq, const float* __restrict__ wk,
    const float* __restrict__ wv, const float* __restrict__ wqf,
    const float* __restrict__ wkf, const float* __restrict__ wvf,
    float* __restrict__ ws) {
  int id = blockIdx.x * 256 + threadIdx.x;           // 512*1152 total
  int i = id / 1152, p = id % 1152;
  const float* w; int col, W; float* dst;
  if (p < 192)      { w = wq;  col = p;     W = 192; dst = ws + O_Q  + i*192 + col; }
  else if (p < 384) { w = wk;  col = p-192; W = 192; dst = ws + O_KT + col*512 + i; }
  else if (p < 576) { w = wv;  col = p-384; W = 192; dst = ws + O_VT + col*512 + i; }
  else if (p < 720) { w = wqf; col = p-576; W = 144; dst = ws + O_QF + i*144 + col; }
  else if (p < 864) { w = wkf; col = p-720; W = 144; dst = ws + O_KF + i*144 + col; }
  else              { w = wvf; col = p-864; W = 288; dst = ws + O_VF + i*288 + col; }
  const float* srow = s + i*CS;
  float acc = 0.f;
  #pragma unroll 8
  for (int k = 0; k < CS; ++k) acc += srow[k] * w[k*W + col];
  *dst = acc;
}

// ---------------- lift local points to global frame ----------------
__global__ __launch_bounds__(256) void k_lift(
    const float* __restrict__ rot, const float* __restrict__ trans,
    float* __restrict__ ws) {
  int id = blockIdx.x * 256 + threadIdx.x;           // 512*192 points
  int i = id / 192, pt = id % 192;
  const float* R = rot + i*9;
  const float* T = trans + i*3;
  if (pt < 48) {
    const float* src = ws + O_QF + i*144 + pt*3;
    float l0 = src[0], l1 = src[1], l2 = src[2];
    float* dst = ws + O_GQ + i*144 + pt*3;
    #pragma unroll
    for (int o = 0; o < 3; ++o)
      dst[o] = R[o*3+0]*l0 + R[o*3+1]*l1 + R[o*3+2]*l2 + T[o];
  } else if (pt < 96) {
    int p3 = pt - 48;
    const float* src = ws + O_KF + i*144 + p3*3;
    float l0 = src[0], l1 = src[1], l2 = src[2];
    #pragma unroll
    for (int o = 0; o < 3; ++o)
      ws[O_GKT + (p3*3+o)*512 + i] = R[o*3+0]*l0 + R[o*3+1]*l1 + R[o*3+2]*l2 + T[o];
  } else {
    int p3 = pt - 96;
    const float* src = ws + O_VF + i*288 + p3*3;
    float l0 = src[0], l1 = src[1], l2 = src[2];
    #pragma unroll
    for (int o = 0; o < 3; ++o)
      ws[O_GVT + (p3*3+o)*512 + i] = R[o*3+0]*l0 + R[o*3+1]*l1 + R[o*3+2]*l2 + T[o];
  }
}

// ---------------- biasT[i][h][j] = z[i,j,:] . w_bias[:,h] ----------------
// 4 lanes per z-row, shuffle combine; coalesced z reads.
__global__ __launch_bounds__(256) void k_bias(
    const float* __restrict__ z, const float* __restrict__ wb,
    float* __restrict__ ws) {
  __shared__ float wbl[CZ*H];
  int t = threadIdx.x;
  for (int idx = t; idx < CZ*H; idx += 256) wbl[idx] = wb[idx];
  __syncthreads();
  int row = blockIdx.x * 64 + (t >> 2);              // global i*512 + j
  int q = t & 3;
  const float4* zr = (const float4*)(z + (size_t)row * CZ) + q;
  float acc[H];
  #pragma unroll
  for (int h = 0; h < H; ++h) acc[h] = 0.f;
  #pragma unroll
  for (int kk = 0; kk < 8; ++kk) {
    float4 v = zr[kk*4];
    int c = (q + kk*4) * 4;
    #pragma unroll
    for (int h = 0; h < H; ++h)
      acc[h] += v.x*wbl[(c+0)*H+h] + v.y*wbl[(c+1)*H+h]
              + v.z*wbl[(c+2)*H+h] + v.w*wbl[(c+3)*H+h];
  }
  #pragma unroll
  for (int h = 0; h < H; ++h) {
    acc[h] += __shfl_xor(acc[h], 1);
    acc[h] += __shfl_xor(acc[h], 2);
  }
  if (q == 0) {
    int i = row >> 9, j = row & 511;
    float* bT = ws + O_BIAS + (size_t)i*6144 + j;
    #pragma unroll
    for (int h = 0; h < H; ++h) bT[(size_t)h*512] = acc[h];
  }
}

// ---------------- scores + softmax, all in registers ----------------
// one block per i; wave w handles heads 3w..3w+2; overwrites biasT with attn.
__global__ __launch_bounds__(256) void k_score(
    const float* __restrict__ hw, float* __restrict__ ws) {
  __shared__ float Qi[192];
  __shared__ float gqi[144];
  __shared__ float coef[H];
  int i = blockIdx.x;
  int t = threadIdx.x;
  int wave = t >> 6, lane = t & 63;
  if (t < 192) Qi[t]  = ws[O_Q  + (size_t)i*192 + t];
  if (t < 144) gqi[t] = ws[O_GQ + (size_t)i*144 + t];
  if (t < H) {
    float x = hw[t];
    float sp = fmaxf(x, 0.f) + log1pf(__expf(-fabsf(x)));  // softplus
    coef[t] = -0.5f * WC * sp;
  }
  __syncthreads();
  float* att = ws + O_BIAS + (size_t)i*6144;
  const float* Kt  = ws + O_KT;
  const float* gkT = ws + O_GKT;
  for (int hh = 0; hh < 3; ++hh) {
    int h = wave*3 + hh;
    float sreg[8];
    float cf = coef[h];
    #pragma unroll
    for (int jb = 0; jb < 8; ++jb) {
      int j = jb*64 + lane;
      float rep = 0.f;
      #pragma unroll
      for (int d = 0; d < 16; ++d) rep += Qi[h*16+d] * Kt[(h*16+d)*512 + j];
      float pt = 0.f;
      #pragma unroll
      for (int r = 0; r < 12; ++r) {
        float df = gqi[h*12+r] - gkT[(h*12+r)*512 + j];
        pt += df*df;
      }
      sreg[jb] = WL * (rep * 0.25f + att[(size_t)h*512 + j] + cf*pt);
    }
    float m = sreg[0];
    #pragma unroll
    for (int jb = 1; jb < 8; ++jb) m = fmaxf(m, sreg[jb]);
    #pragma unroll
    for (int off = 32; off; off >>= 1) m = fmaxf(m, __shfl_xor(m, off));
    float e = 0.f;
    #pragma unroll
    for (int jb = 0; jb < 8; ++jb) { sreg[jb] = __expf(sreg[jb] - m); e += sreg[jb]; }
    #pragma unroll
    for (int off = 32; off; off >>= 1) e += __shfl_xor(e, off);
    float inv = 1.f / e;
    #pragma unroll
    for (int jb = 0; jb < 8; ++jb) att[(size_t)h*512 + jb*64 + lane] = sreg[jb] * inv;
  }
}

// ---------------- apply attention: out_rep, points, out_pair ----------------
__global__ __launch_bounds__(256) void k_apply(
    const float* __restrict__ z, const float* __restrict__ rot,
    const float* __restrict__ trans, float* __restrict__ ws) {
  __shared__ float aL[H*ALD];        // attn row, padded stride
  __shared__ float pairOdd[H*128];
  __shared__ float tmpP[H*PV*3];
  int i = blockIdx.x;
  int t = threadIdx.x;
  const float* attn = ws + O_BIAS + (size_t)i*6144;
  for (int idx = t; idx < 6144; idx += 256)
    aL[(idx >> 9)*ALD + (idx & 511)] = attn[idx];
  __syncthreads();
  float* cat = ws + O_CAT + (size_t)i*CAT_W;

  // out_rep (192) + tmp points (288): float4 dot of attn row with VT/gvT rows
  for (int task = t; task < 480; task += 256) {
    int u, h; const float* src;
    if (task < 192) { u = task;       h = u >> 4; src = ws + O_VT  + (size_t)u*512; }
    else            { u = task - 192; h = u / 24; src = ws + O_GVT + (size_t)u*512; }
    const float4* a4 = (const float4*)(aL + h*ALD);
    const float4* s4 = (const float4*)src;
    float4 acc4 = {0.f, 0.f, 0.f, 0.f};
    #pragma unroll 8
    for (int j4 = 0; j4 < 128; ++j4) {
      float4 a = a4[j4], v = s4[j4];
      acc4.x += a.x*v.x; acc4.y += a.y*v.y; acc4.z += a.z*v.z; acc4.w += a.w*v.w;
    }
    float acc = (acc4.x + acc4.y) + (acc4.z + acc4.w);
    if (task < 192) cat[u] = acc; else tmpP[u] = acc;
  }

  // out_pair: coalesced z loop, even/odd j split
  {
    int c = t & 127, g = t >> 7;
    float acc[H];
    #pragma unroll
    for (int h = 0; h < H; ++h) acc[h] = 0.f;
    const float* zr = z + (size_t)i*N*CZ + c;
    #pragma unroll 4
    for (int jj = 0; jj < 256; ++jj) {
      int j = jj*2 + g;
      float zv = zr[(size_t)j*CZ];
      #pragma unroll
      for (int h = 0; h < H; ++h) acc[h] += aL[h*ALD + j] * zv;
    }
    if (g) {
      #pragma unroll
      for (int h = 0; h < H; ++h) pairOdd[h*128 + c] = acc[h];
    }
    __syncthreads();
    if (!g) {
      #pragma unroll
      for (int h = 0; h < H; ++h) cat[576 + h*128 + c] = acc[h] + pairOdd[h*128 + c];
    }
  }

  // frame-inverse + norms
  if (t < 96) {
    int h = t >> 3, q = t & 7;
    const float* R = rot + i*9;
    float tp[3];
    #pragma unroll
    for (int p = 0; p < 3; ++p) tp[p] = tmpP[h*24 + q*3 + p] - trans[i*3 + p];
    float nrm = 1e-8f;
    #pragma unroll
    for (int o = 0; o < 3; ++o) {
      float v = R[o]*tp[0] + R[3+o]*tp[1] + R[6+o]*tp[2];
      cat[192 + h*24 + q*3 + o] = v;
      nrm += v*v;
    }
    cat[480 + h*8 + q] = sqrtf(nrm);
  }
}

// ---------------- final GEMM stage 1: partials over K chunks ----------------
__global__ __launch_bounds__(128) void k_out_part(
    const float* __restrict__ wo, const float* __restrict__ ws,
    float* __restrict__ part) {
  __shared__ float catT[KCH][16];        // transposed: [k][row]
  int rt = blockIdx.x, ct = blockIdx.y, kc = blockIdx.z;
  int t = threadIdx.x;
  int i0 = rt * 16;
  int c  = ct * 128 + t;
  int k0 = kc * KCH;
  const float* cat = ws + O_CAT;
  for (int idx = t; idx < 16*KCH; idx += 128) {
    int r = idx / KCH, k = idx % KCH;
    catT[k][r] = cat[(size_t)(i0 + r) * CAT_W + k0 + k];
  }
  __syncthreads();
  float acc[16];
  #pragma unroll
  for (int r = 0; r < 16; ++r) acc[r] = 0.f;
  const float* wp = wo + (size_t)k0 * 384 + c;
  #pragma unroll 4
  for (int k = 0; k < KCH; ++k) {
    float wv = wp[(size_t)k * 384];
    const float* a = catT[k];
    #pragma unroll
    for (int r = 0; r < 16; ++r) acc[r] += a[r] * wv;
  }
  float* dst = part + (size_t)kc * (N*CS) + (size_t)i0 * 384 + c;
  #pragma unroll
  for (int r = 0; r < 16; ++r) dst[(size_t)r * 384] = acc[r];
}

// ---------------- final GEMM stage 2: reduce partials + bias ----------------
__global__ __launch_bounds__(256) void k_out_red(
    const float* __restrict__ bo, const float* __restrict__ ws,
    float* __restrict__ out) {
  int id = blockIdx.x * 256 + threadIdx.x;   // 49152 float4 tasks
  int c4 = id % 96;
  float4 acc = ((const float4*)bo)[c4];
  const float* part = ws + O_PART;
  #pragma unroll
  for (int s = 0; s < KSPLIT; ++s) {
    float4 p = *(const float4*)(part + (size_t)s * (N*CS) + (size_t)id * 4);
    acc.x += p.x; acc.y += p.y; acc.z += p.z; acc.w += p.w;
  }
  ((float4*)out)[id] = acc;
}

extern "C" void kernel_launch(void* const* d_in, const int* in_sizes, int n_in,
                              void* d_out, int out_size, void* d_ws, size_t ws_size,
                              hipStream_t stream) {
  const float* s     = (const float*)d_in[0];
  const float* z     = (const float*)d_in[1];
  const float* rot   = (const float*)d_in[2];
  const float* trans = (const float*)d_in[3];
  const float* wq    = (const float*)d_in[4];
  const float* wk    = (const float*)d_in[5];
  const float* wv    = (const float*)d_in[6];
  const float* wqf   = (const float*)d_in[7];
  const float* wkf   = (const float*)d_in[8];
  const float* wvf   = (const float*)d_in[9];
  const float* wb    = (const float*)d_in[10];
  const float* hw    = (const float*)d_in[11];
  const float* wo    = (const float*)d_in[12];
  const float* bo    = (const float*)d_in[13];
  float* out = (float*)d_out;
  float* ws  = (float*)d_ws;

  hipLaunchKernelGGL(k_proj, dim3(512*1152/256), dim3(256), 0, stream,
                     s, wq, wk, wv, wqf, wkf, wvf, ws);
  hipLaunchKernelGGL(k_lift, dim3(512*192/256), dim3(256), 0, stream,
                     rot, trans, ws);
  hipLaunchKernelGGL(k_bias, dim3(512*512/64), dim3(256), 0, stream,
                     z, wb, ws);
  hipLaunchKernelGGL(k_score, dim3(512), dim3(256), 0, stream,
                     hw, ws);
  hipLaunchKernelGGL(k_apply, dim3(512), dim3(256), 0, stream,
                     z, rot, trans, ws);
  hipLaunchKernelGGL(k_out_part, dim3(32, 3, KSPLIT), dim3(128), 0, stream,
                     wo, ws, ws + O_PART);
  hipLaunchKernelGGL(k_out_red, dim3(192), dim3(256), 0, stream,
                     bo, ws, out);
}

// Round 4
// 398.166 us; speedup vs baseline: 1.2498x; 1.2498x over previous
//
#include <hip/hip_runtime.h>
#include <math.h>

#define N    512
#define CS   384
#define CZ   128
#define H    12
#define D    16
#define PQ   4
#define PV   8
#define CAT_W 2112

#define WC 0.23570226039551584f  /* sqrt(2/(9*4)) */
#define WL 0.5773502691896258f   /* sqrt(1/3) */

// workspace offsets (in floats)
#define O_Q    0          /* Q   [512][192] row-major */
#define O_KT   98304      /* Kt  [192][512] transposed */
#define O_VT   196608     /* VT  [192][512] transposed */
#define O_QF   294912     /* raw local points [512][144] */
#define O_KF   368640
#define O_VF   442368     /* [512][288] */
#define O_GQ   589824     /* gq  [512][144] row-major */
#define O_GKT  663552     /* gkT [144][512] transposed */
#define O_GVT  737280     /* gvT [288][512] transposed */
#define O_BIAS 884736     /* biasT->attn [512][12][512]; reused for k_out partials */
#define O_PART O_BIAS
#define O_CAT  4030464    /* [512][2112] */

#define KSPLIT 8
#define KCH    264        /* 2112 / 8 */
#define ALD    520        /* padded LDS stride for attn rows */

// ---------------- projections: s @ {w_q,w_k,w_v,w_qf,w_kf,w_vf} ----------------
// thread = (i0, col-quad); handles rows i0 and i0+256 (weight reuse).
__global__ __launch_bounds__(256) void k_proj(
    const float* __restrict__ s,
    const float* __restrict__ wq, const float* __restrict__ wk,
    const float* __restrict__ wv, const float* __restrict__ wqf,
    const float* __restrict__ wkf, const float* __restrict__ wvf,
    float* __restrict__ ws) {
  int id = blockIdx.x * 256 + threadIdx.x;   // 256 i0 * 288 c4 = 73728
  int i0 = id / 288;
  int c4 = id % 288;
  int col = c4 * 4;
  const float* w; int cc, W, kind;
  if (col < 192)      { w = wq;  cc = col;     W = 192; kind = 0; }
  else if (col < 384) { w = wk;  cc = col-192; W = 192; kind = 1; }
  else if (col < 576) { w = wv;  cc = col-384; W = 192; kind = 2; }
  else if (col < 720) { w = wqf; cc = col-576; W = 144; kind = 3; }
  else if (col < 864) { w = wkf; cc = col-720; W = 144; kind = 4; }
  else                { w = wvf; cc = col-864; W = 288; kind = 5; }
  const float* s0 = s + (size_t)i0 * CS;
  const float* s1 = s0 + 256 * CS;
  float4 a0 = {0,0,0,0}, a1 = {0,0,0,0};
  #pragma unroll 8
  for (int k = 0; k < CS; ++k) {
    float4 wv4 = *(const float4*)(w + (size_t)k * W + cc);
    float x0 = s0[k], x1 = s1[k];
    a0.x += x0*wv4.x; a0.y += x0*wv4.y; a0.z += x0*wv4.z; a0.w += x0*wv4.w;
    a1.x += x1*wv4.x; a1.y += x1*wv4.y; a1.z += x1*wv4.z; a1.w += x1*wv4.w;
  }
  int i1 = i0 + 256;
  if (kind == 0) {
    *(float4*)(ws + O_Q + (size_t)i0*192 + cc) = a0;
    *(float4*)(ws + O_Q + (size_t)i1*192 + cc) = a1;
  } else if (kind == 1) {
    ws[O_KT + (size_t)(cc+0)*512 + i0] = a0.x; ws[O_KT + (size_t)(cc+1)*512 + i0] = a0.y;
    ws[O_KT + (size_t)(cc+2)*512 + i0] = a0.z; ws[O_KT + (size_t)(cc+3)*512 + i0] = a0.w;
    ws[O_KT + (size_t)(cc+0)*512 + i1] = a1.x; ws[O_KT + (size_t)(cc+1)*512 + i1] = a1.y;
    ws[O_KT + (size_t)(cc+2)*512 + i1] = a1.z; ws[O_KT + (size_t)(cc+3)*512 + i1] = a1.w;
  } else if (kind == 2) {
    ws[O_VT + (size_t)(cc+0)*512 + i0] = a0.x; ws[O_VT + (size_t)(cc+1)*512 + i0] = a0.y;
    ws[O_VT + (size_t)(cc+2)*512 + i0] = a0.z; ws[O_VT + (size_t)(cc+3)*512 + i0] = a0.w;
    ws[O_VT + (size_t)(cc+0)*512 + i1] = a1.x; ws[O_VT + (size_t)(cc+1)*512 + i1] = a1.y;
    ws[O_VT + (size_t)(cc+2)*512 + i1] = a1.z; ws[O_VT + (size_t)(cc+3)*512 + i1] = a1.w;
  } else if (kind == 3) {
    *(float4*)(ws + O_QF + (size_t)i0*144 + cc) = a0;
    *(float4*)(ws + O_QF + (size_t)i1*144 + cc) = a1;
  } else if (kind == 4) {
    *(float4*)(ws + O_KF + (size_t)i0*144 + cc) = a0;
    *(float4*)(ws + O_KF + (size_t)i1*144 + cc) = a1;
  } else {
    *(float4*)(ws + O_VF + (size_t)i0*288 + cc) = a0;
    *(float4*)(ws + O_VF + (size_t)i1*288 + cc) = a1;
  }
}

// ---------------- lift local points to global frame ----------------
__global__ __launch_bounds__(256) void k_lift(
    const float* __restrict__ rot, const float* __restrict__ trans,
    float* __restrict__ ws) {
  int id = blockIdx.x * 256 + threadIdx.x;           // 512*192 points
  int i = id / 192, pt = id % 192;
  const float* R = rot + i*9;
  const float* T = trans + i*3;
  if (pt < 48) {
    const float* src = ws + O_QF + i*144 + pt*3;
    float l0 = src[0], l1 = src[1], l2 = src[2];
    float* dst = ws + O_GQ + i*144 + pt*3;
    #pragma unroll
    for (int o = 0; o < 3; ++o)
      dst[o] = R[o*3+0]*l0 + R[o*3+1]*l1 + R[o*3+2]*l2 + T[o];
  } else if (pt < 96) {
    int p3 = pt - 48;
    const float* src = ws + O_KF + i*144 + p3*3;
    float l0 = src[0], l1 = src[1], l2 = src[2];
    #pragma unroll
    for (int o = 0; o < 3; ++o)
      ws[O_GKT + (size_t)(p3*3+o)*512 + i] = R[o*3+0]*l0 + R[o*3+1]*l1 + R[o*3+2]*l2 + T[o];
  } else {
    int p3 = pt - 96;
    const float* src = ws + O_VF + i*288 + p3*3;
    float l0 = src[0], l1 = src[1], l2 = src[2];
    #pragma unroll
    for (int o = 0; o < 3; ++o)
      ws[O_GVT + (size_t)(p3*3+o)*512 + i] = R[o*3+0]*l0 + R[o*3+1]*l1 + R[o*3+2]*l2 + T[o];
  }
}

// ---------------- biasT[i][h][j] = z[i,j,:] . w_bias[:,h] ----------------
__global__ __launch_bounds__(256) void k_bias(
    const float* __restrict__ z, const float* __restrict__ wb,
    float* __restrict__ ws) {
  __shared__ float wbl[CZ*H];
  int t = threadIdx.x;
  for (int idx = t; idx < CZ*H; idx += 256) wbl[idx] = wb[idx];
  __syncthreads();
  int row = blockIdx.x * 64 + (t >> 2);              // global i*512 + j
  int q = t & 3;
  const float4* zr = (const float4*)(z + (size_t)row * CZ) + q;
  float acc[H];
  #pragma unroll
  for (int h = 0; h < H; ++h) acc[h] = 0.f;
  #pragma unroll
  for (int kk = 0; kk < 8; ++kk) {
    float4 v = zr[kk*4];
    int c = (q + kk*4) * 4;
    #pragma unroll
    for (int h = 0; h < H; ++h)
      acc[h] += v.x*wbl[(c+0)*H+h] + v.y*wbl[(c+1)*H+h]
              + v.z*wbl[(c+2)*H+h] + v.w*wbl[(c+3)*H+h];
  }
  #pragma unroll
  for (int h = 0; h < H; ++h) {
    acc[h] += __shfl_xor(acc[h], 1);
    acc[h] += __shfl_xor(acc[h], 2);
  }
  if (q == 0) {
    int i = row >> 9, j = row & 511;
    float* bT = ws + O_BIAS + (size_t)i*6144 + j;
    #pragma unroll
    for (int h = 0; h < H; ++h) bT[(size_t)h*512] = acc[h];
  }
}

// ---------------- scores + softmax, one wave per head ----------------
__global__ __launch_bounds__(768) void k_score(
    const float* __restrict__ hw, float* __restrict__ ws) {
  __shared__ float Qi[192];
  __shared__ float gqi[144];
  int i = blockIdx.x;
  int t = threadIdx.x;
  int h = t >> 6, lane = t & 63;                 // 12 waves = 12 heads
  if (t < 192) Qi[t]  = ws[O_Q  + (size_t)i*192 + t];
  else if (t >= 256 && t < 400) gqi[t-256] = ws[O_GQ + (size_t)i*144 + (t-256)];
  float x = hw[h];
  float sp = fmaxf(x, 0.f) + log1pf(__expf(-fabsf(x)));   // softplus
  float cf = -0.5f * WC * sp;
  __syncthreads();
  float* att = ws + O_BIAS + (size_t)i*6144 + (size_t)h*512;
  const float* Kt  = ws + O_KT  + (size_t)h*16*512;
  const float* gkT = ws + O_GKT + (size_t)h*12*512;
  const float* Qr  = Qi + h*16;
  const float* gqr = gqi + h*12;
  float sreg[8];
  #pragma unroll
  for (int jb = 0; jb < 8; ++jb) {
    int j = jb*64 + lane;
    float rep = 0.f;
    #pragma unroll
    for (int d = 0; d < 16; ++d) rep += Qr[d] * Kt[(size_t)d*512 + j];
    float pt = 0.f;
    #pragma unroll
    for (int r = 0; r < 12; ++r) {
      float df = gqr[r] - gkT[(size_t)r*512 + j];
      pt += df*df;
    }
    sreg[jb] = WL * (rep * 0.25f + att[j] + cf*pt);
  }
  float m = sreg[0];
  #pragma unroll
  for (int jb = 1; jb < 8; ++jb) m = fmaxf(m, sreg[jb]);
  #pragma unroll
  for (int off = 32; off; off >>= 1) m = fmaxf(m, __shfl_xor(m, off));
  float e = 0.f;
  #pragma unroll
  for (int jb = 0; jb < 8; ++jb) { sreg[jb] = __expf(sreg[jb] - m); e += sreg[jb]; }
  #pragma unroll
  for (int off = 32; off; off >>= 1) e += __shfl_xor(e, off);
  float inv = 1.f / e;
  #pragma unroll
  for (int jb = 0; jb < 8; ++jb) att[jb*64 + lane] = sreg[jb] * inv;
}

// ---------------- apply attention: out_rep + points (waves 0-7), out_pair (waves 8-11) ----------------
__global__ __launch_bounds__(768) void k_apply2(
    const float* __restrict__ z, const float* __restrict__ rot,
    const float* __restrict__ trans, float* __restrict__ ws) {
  __shared__ float aL[H*ALD];        // attn, padded stride 520
  __shared__ float tmpP[H*PV*3];
  int i = blockIdx.x;
  int t = threadIdx.x;
  const float* attn = ws + O_BIAS + (size_t)i*6144;
  for (int idx = t; idx < 6144; idx += 768)
    aL[(idx >> 9)*ALD + (idx & 511)] = attn[idx];
  __syncthreads();
  float* cat = ws + O_CAT + (size_t)i*CAT_W;

  if (t < 512) {
    // out_rep (192 tasks) + tmp points (288 tasks), 8-way j-split + shfl reduce
    int u0 = t >> 3, jg = t & 7;
    for (int round = 0; round < 8; ++round) {
      int u = round*64 + u0;
      if (u < 480) {
        int h; const float* src;
        if (u < 192) { h = u >> 4;            src = ws + O_VT  + (size_t)u*512; }
        else         { int v = u-192; h = v/24; src = ws + O_GVT + (size_t)v*512; }
        const float4* s4 = (const float4*)src;
        const float4* a4 = (const float4*)(aL + h*ALD);
        float4 acc = {0,0,0,0};
        #pragma unroll
        for (int jj = 0; jj < 16; ++jj) {
          int j4 = jj*8 + jg;
          float4 a = a4[j4], v = s4[j4];
          acc.x += a.x*v.x; acc.y += a.y*v.y; acc.z += a.z*v.z; acc.w += a.w*v.w;
        }
        float r = (acc.x + acc.y) + (acc.z + acc.w);
        r += __shfl_xor(r, 1); r += __shfl_xor(r, 2); r += __shfl_xor(r, 4);
        if (jg == 0) {
          if (u < 192) cat[u] = r; else tmpP[u-192] = r;
        }
      }
    }
  } else {
    // out_pair: thread = (c4 = tp>>3 in [0,32), jg = tp&7); coalesced z, shfl reduce over jg
    int tp = t - 512;
    int jg = tp & 7, c4 = tp >> 3;
    const float4* z4 = (const float4*)(z + (size_t)i*N*CZ);
    float4 pacc[H];
    #pragma unroll
    for (int h = 0; h < H; ++h) pacc[h] = make_float4(0.f,0.f,0.f,0.f);
    #pragma unroll 4
    for (int jj = 0; jj < 64; ++jj) {
      int j = jj*8 + jg;
      float4 zv = z4[j*32 + c4];
      #pragma unroll
      for (int h = 0; h < H; ++h) {
        float a = aL[h*ALD + j];
        pacc[h].x += a*zv.x; pacc[h].y += a*zv.y;
        pacc[h].z += a*zv.z; pacc[h].w += a*zv.w;
      }
    }
    #pragma unroll
    for (int h = 0; h < H; ++h) {
      #pragma unroll
      for (int off = 1; off <= 4; off <<= 1) {
        pacc[h].x += __shfl_xor(pacc[h].x, off);
        pacc[h].y += __shfl_xor(pacc[h].y, off);
        pacc[h].z += __shfl_xor(pacc[h].z, off);
        pacc[h].w += __shfl_xor(pacc[h].w, off);
      }
    }
    if (jg == 0) {
      float4* dst = (float4*)(cat + 576);
      #pragma unroll
      for (int h = 0; h < H; ++h) dst[h*32 + c4] = pacc[h];
    }
  }
  __syncthreads();

  // frame-inverse + norms
  if (t < 96) {
    int h = t >> 3, q = t & 7;
    const float* R = rot + i*9;
    float tp[3];
    #pragma unroll
    for (int p = 0; p < 3; ++p) tp[p] = tmpP[h*24 + q*3 + p] - trans[i*3 + p];
    float nrm = 1e-8f;
    #pragma unroll
    for (int o = 0; o < 3; ++o) {
      float v = R[o]*tp[0] + R[3+o]*tp[1] + R[6+o]*tp[2];
      cat[192 + h*24 + q*3 + o] = v;
      nrm += v*v;
    }
    cat[480 + h*8 + q] = sqrtf(nrm);
  }
}

// ---------------- final GEMM stage 1: partials over K chunks ----------------
__global__ __launch_bounds__(128) void k_out_part(
    const float* __restrict__ wo, const float* __restrict__ ws,
    float* __restrict__ part) {
  __shared__ float catT[KCH][16];
  int rt = blockIdx.x, ct = blockIdx.y, kc = blockIdx.z;
  int t = threadIdx.x;
  int i0 = rt * 16;
  int c  = ct * 128 + t;
  int k0 = kc * KCH;
  const float* cat = ws + O_CAT;
  for (int idx = t; idx < 16*KCH; idx += 128) {
    int r = idx / KCH, k = idx % KCH;
    catT[k][r] = cat[(size_t)(i0 + r) * CAT_W + k0 + k];
  }
  __syncthreads();
  float acc[16];
  #pragma unroll
  for (int r = 0; r < 16; ++r) acc[r] = 0.f;
  const float* wp = wo + (size_t)k0 * 384 + c;
  #pragma unroll 4
  for (int k = 0; k < KCH; ++k) {
    float wv = wp[(size_t)k * 384];
    const float* a = catT[k];
    #pragma unroll
    for (int r = 0; r < 16; ++r) acc[r] += a[r] * wv;
  }
  float* dst = part + (size_t)kc * (N*CS) + (size_t)i0 * 384 + c;
  #pragma unroll
  for (int r = 0; r < 16; ++r) dst[(size_t)r * 384] = acc[r];
}

// ---------------- final GEMM stage 2: reduce partials + bias ----------------
__global__ __launch_bounds__(256) void k_out_red(
    const float* __restrict__ bo, const float* __restrict__ ws,
    float* __restrict__ out) {
  int id = blockIdx.x * 256 + threadIdx.x;   // 49152 float4 tasks
  int c4 = id % 96;
  float4 acc = ((const float4*)bo)[c4];
  const float* part = ws + O_PART;
  #pragma unroll
  for (int s = 0; s < KSPLIT; ++s) {
    float4 p = *(const float4*)(part + (size_t)s * (N*CS) + (size_t)id * 4);
    acc.x += p.x; acc.y += p.y; acc.z += p.z; acc.w += p.w;
  }
  ((float4*)out)[id] = acc;
}

extern "C" void kernel_launch(void* const* d_in, const int* in_sizes, int n_in,
                              void* d_out, int out_size, void* d_ws, size_t ws_size,
                              hipStream_t stream) {
  const float* s     = (const float*)d_in[0];
  const float* z     = (const float*)d_in[1];
  const float* rot   = (const float*)d_in[2];
  const float* trans = (const float*)d_in[3];
  const float* wq    = (const float*)d_in[4];
  const float* wk    = (const float*)d_in[5];
  const float* wv    = (const float*)d_in[6];
  const float* wqf   = (const float*)d_in[7];
  const float* wkf   = (const float*)d_in[8];
  const float* wvf   = (const float*)d_in[9];
  const float* wb    = (const float*)d_in[10];
  const float* hw    = (const float*)d_in[11];
  const float* wo    = (const float*)d_in[12];
  const float* bo    = (const float*)d_in[13];
  float* out = (float*)d_out;
  float* ws  = (float*)d_ws;

  hipLaunchKernelGGL(k_proj, dim3(288), dim3(256), 0, stream,
                     s, wq, wk, wv, wqf, wkf, wvf, ws);
  hipLaunchKernelGGL(k_lift, dim3(384), dim3(256), 0, stream,
                     rot, trans, ws);
  hipLaunchKernelGGL(k_bias, dim3(4096), dim3(256), 0, stream,
                     z, wb, ws);
  hipLaunchKernelGGL(k_score, dim3(512), dim3(768), 0, stream,
                     hw, ws);
  hipLaunchKernelGGL(k_apply2, dim3(512), dim3(768), 0, stream,
                     z, rot, trans, ws);
  hipLaunchKernelGGL(k_out_part, dim3(32, 3, KSPLIT), dim3(128), 0, stream,
                     wo, ws, ws + O_PART);
  hipLaunchKernelGGL(k_out_red, dim3(192), dim3(256), 0, stream,
                     bo, ws, out);
}